// Round 5
// baseline (510.445 us; speedup 1.0000x reference)
//
#include <hip/hip_runtime.h>
#include <hip/hip_bf16.h>

#define DIN 96
#define DOUT 32
#define NH 4
#define DTOT 128          // NH * DOUT, concat output width
#define SLOPE 0.2f
#define NPB 16            // nodes per block in feat_kernel
#define BSH 7             // bucket shift: 128 src nodes per bucket
#define BNODES 128
#define MAXB 1024         // max buckets (N <= 131072)
#define EPB 4096          // edges per block in bin kernels (782 blocks ~ 3/CU)
#define CPAD 16           // counter padding: one counter per 64B line

// pack two fp32 -> two bf16 (RNE) in one uint
__device__ __forceinline__ unsigned int packbf2(float lo, float hi) {
    unsigned int a = __float_as_uint(lo), b = __float_as_uint(hi);
    a += 0x7fffu + ((a >> 16) & 1u);
    b += 0x7fffu + ((b >> 16) & 1u);
    return (a >> 16) | (b & 0xffff0000u);
}

// ---------------------------------------------------------------------------
// Kernel A: h[n] = x[n] @ W (all heads) stored as packed bf16, plus per-node
// attention exp factors:
//   usrc[n*4+head] = (exp(-as), exp(-0.2*as)),  as = h[n,head]·a[head,:32]
//   vdst[n*4+head] = (exp(-ad), exp(-0.2*ad))
// Edge coefficient ee = exp(-leaky(as+ad)) = min(u.x*v.x, u.y*v.y).
// ---------------------------------------------------------------------------
__global__ __launch_bounds__(256) void feat_kernel(
    const float* __restrict__ x, const float* __restrict__ W,
    const float* __restrict__ a,
    unsigned int* __restrict__ hq,      // [N*64] packed bf16 pairs
    float2* __restrict__ usrc, float2* __restrict__ vdst,
    int n_nodes)
{
    __shared__ float Wl[DIN * DTOT];
    __shared__ float xs[NPB * DIN];
    __shared__ float al[NH * 2 * DOUT];
    const int t = threadIdx.x;

    for (int i = t; i < DIN * DTOT; i += 256) {
        int k = i >> 7, c = i & 127;
        int head = c >> 5, j = c & 31;
        Wl[i] = W[head * (DIN * DOUT) + k * DOUT + j];
    }
    for (int i = t; i < NH * 2 * DOUT; i += 256) al[i] = a[i];

    const int node0 = blockIdx.x * NPB;
    for (int i = t; i < NPB * DIN; i += 256) {
        int gidx = node0 * DIN + i;
        xs[i] = (gidx < n_nodes * DIN) ? x[gidx] : 0.f;
    }
    __syncthreads();

    const int node = t >> 4;
    const int cb = (t & 15) << 3;
    float acc[8];
#pragma unroll
    for (int j = 0; j < 8; ++j) acc[j] = 0.f;

#pragma unroll 4
    for (int k = 0; k < DIN; ++k) {
        float xv = xs[node * DIN + k];
#pragma unroll
        for (int j = 0; j < 8; ++j)
            acc[j] += xv * Wl[k * DTOT + cb + j];
    }

    const int g = node0 + node;
    if (g < n_nodes) {
        uint4 pk;
        pk.x = packbf2(acc[0], acc[1]);
        pk.y = packbf2(acc[2], acc[3]);
        pk.z = packbf2(acc[4], acc[5]);
        pk.w = packbf2(acc[6], acc[7]);
        *(uint4*)&hq[(size_t)g * 64 + (cb >> 1)] = pk;
    }

    const int head = cb >> 5;
    const int j0 = cb & 31;
    float ps = 0.f, pd = 0.f;
#pragma unroll
    for (int j = 0; j < 8; ++j) {
        ps += acc[j] * al[head * 64 + j0 + j];
        pd += acc[j] * al[head * 64 + 32 + j0 + j];
    }
    ps += __shfl_xor(ps, 1); ps += __shfl_xor(ps, 2);
    pd += __shfl_xor(pd, 1); pd += __shfl_xor(pd, 2);
    if ((t & 3) == 0 && g < n_nodes) {
        usrc[g * NH + head] = make_float2(__expf(-ps), __expf(-SLOPE * ps));
        vdst[g * NH + head] = make_float2(__expf(-pd), __expf(-SLOPE * pd));
    }
}

// ---------------------------------------------------------------------------
// Two-level counting sort of edges by src.
// ---------------------------------------------------------------------------

// count edges per coarse bucket; counts padded to 1 per 64B line
__global__ __launch_bounds__(256) void bincount_kernel(
    const int* __restrict__ esrc, int* __restrict__ counts, int n_edges, int nb)
{
    __shared__ int bc[MAXB];
    const int t = threadIdx.x;
    for (int i = t; i < nb; i += 256) bc[i] = 0;
    __syncthreads();
    const int base = blockIdx.x * EPB;
    const int end = min(base + EPB, n_edges);
    int i = base + (t << 2);
    for (; i + 3 < end; i += 1024) {
        int4 s4 = *(const int4*)(esrc + i);
        atomicAdd(&bc[s4.x >> BSH], 1);
        atomicAdd(&bc[s4.y >> BSH], 1);
        atomicAdd(&bc[s4.z >> BSH], 1);
        atomicAdd(&bc[s4.w >> BSH], 1);
    }
    for (; i < end; ++i) atomicAdd(&bc[esrc[i] >> BSH], 1);
    __syncthreads();
    for (int k = t; k < nb; k += 256)
        if (bc[k] > 0) atomicAdd(&counts[k * CPAD], bc[k]);
}

// scan buckets: bbase (4-aligned binned layout), gcur (padded cursor),
// sbase (4-aligned slots layout with +512 pad slack per bucket)
__global__ __launch_bounds__(1024) void bscan_kernel(
    const int* __restrict__ counts, int* __restrict__ bbase,
    int* __restrict__ gcur, int* __restrict__ sbase, int nb)
{
    __shared__ int tmp[1024];
    const int t = threadIdx.x;
    int v = (t < nb) ? counts[t * CPAD] : 0;
    tmp[t] = v;
    __syncthreads();
    for (int off = 1; off < 1024; off <<= 1) {
        int xv = (t >= off) ? tmp[t - off] : 0;
        __syncthreads();
        tmp[t] += xv;
        __syncthreads();
    }
    if (t < nb) {
        int excl = tmp[t] - v;
        int ab = ((excl + 3) & ~3) + t * 4;   // 4-aligned, disjoint regions
        bbase[t] = ab;
        gcur[t * CPAD] = ab;
        sbase[t] = ((excl + 3) & ~3) + t * (4 * BNODES);
    }
}

// scatter edges (packed srcl|dst) into coarse bucket regions (run-reserved)
__global__ __launch_bounds__(256) void binscatter_kernel(
    const int* __restrict__ esrc, const int* __restrict__ edst,
    int* __restrict__ gcur, unsigned int* __restrict__ binned,
    int n_edges, int nb)
{
    __shared__ int bc[MAXB];
    const int t = threadIdx.x;
    for (int i = t; i < nb; i += 256) bc[i] = 0;
    __syncthreads();
    const int base = blockIdx.x * EPB;
    const int end = min(base + EPB, n_edges);
    int i = base + (t << 2);
    for (; i + 3 < end; i += 1024) {
        int4 s4 = *(const int4*)(esrc + i);
        atomicAdd(&bc[s4.x >> BSH], 1);
        atomicAdd(&bc[s4.y >> BSH], 1);
        atomicAdd(&bc[s4.z >> BSH], 1);
        atomicAdd(&bc[s4.w >> BSH], 1);
    }
    for (; i < end; ++i) atomicAdd(&bc[esrc[i] >> BSH], 1);
    __syncthreads();
    // reserve a contiguous run per non-empty bucket; bc becomes running cursor
    for (int k = t; k < nb; k += 256) {
        int c = bc[k];
        bc[k] = (c > 0) ? atomicAdd(&gcur[k * CPAD], c) : 0;
    }
    __syncthreads();
    i = base + (t << 2);
    for (; i + 3 < end; i += 1024) {
        int4 s4 = *(const int4*)(esrc + i);
        int4 d4 = *(const int4*)(edst + i);
        int p0 = atomicAdd(&bc[s4.x >> BSH], 1);
        int p1 = atomicAdd(&bc[s4.y >> BSH], 1);
        int p2 = atomicAdd(&bc[s4.z >> BSH], 1);
        int p3 = atomicAdd(&bc[s4.w >> BSH], 1);
        binned[p0] = ((unsigned int)(s4.x & (BNODES - 1)) << 17) | (unsigned int)d4.x;
        binned[p1] = ((unsigned int)(s4.y & (BNODES - 1)) << 17) | (unsigned int)d4.y;
        binned[p2] = ((unsigned int)(s4.z & (BNODES - 1)) << 17) | (unsigned int)d4.z;
        binned[p3] = ((unsigned int)(s4.w & (BNODES - 1)) << 17) | (unsigned int)d4.w;
    }
    for (; i < end; ++i) {
        int s = esrc[i];
        int pos = atomicAdd(&bc[s >> BSH], 1);
        binned[pos] = ((unsigned int)(s & (BNODES - 1)) << 17) | (unsigned int)edst[i];
    }
}

// per-bucket fine sort: LDS per-node hist + scan, write offs/deg and slots
__global__ __launch_bounds__(256) void binfine_kernel(
    const unsigned int* __restrict__ binned,
    const int* __restrict__ counts, const int* __restrict__ bbase,
    const int* __restrict__ sbase,
    int* __restrict__ offs, int* __restrict__ deg,
    int* __restrict__ slots, int n_nodes)
{
    __shared__ int dcnt[BNODES];
    __shared__ int sc[BNODES];
    __shared__ int dcur[BNODES];
    const int t = threadIdx.x;
    const int b = blockIdx.x;
    const int cnt = counts[b * CPAD];
    const int start = bbase[b];     // 4-aligned
    const int sb = sbase[b];
    const int node0 = b << BSH;

    if (t < BNODES) dcnt[t] = 0;
    __syncthreads();
    int i = t << 2;
    for (; i + 3 < cnt; i += 1024) {
        uint4 w4 = *(const uint4*)(binned + start + i);
        atomicAdd(&dcnt[w4.x >> 17], 1);
        atomicAdd(&dcnt[w4.y >> 17], 1);
        atomicAdd(&dcnt[w4.z >> 17], 1);
        atomicAdd(&dcnt[w4.w >> 17], 1);
    }
    for (; i < cnt; ++i) atomicAdd(&dcnt[binned[start + i] >> 17], 1);
    __syncthreads();
    int pd = 0;
    if (t < BNODES) { pd = (dcnt[t] + 3) & ~3; sc[t] = pd; }
    __syncthreads();
    for (int off = 1; off < BNODES; off <<= 1) {
        int v = 0;
        if (t < BNODES && t >= off) v = sc[t - off];
        __syncthreads();
        if (t < BNODES) sc[t] += v;
        __syncthreads();
    }
    if (t < BNODES) {
        int o = sb + sc[t] - pd;   // 4-aligned per-node start
        dcur[t] = o;
        int node = node0 + t;
        if (node < n_nodes) { offs[node] = o; deg[node] = dcnt[t]; }
    }
    __syncthreads();
    i = t << 2;
    for (; i + 3 < cnt; i += 1024) {
        uint4 w4 = *(const uint4*)(binned + start + i);
        int p0 = atomicAdd(&dcur[w4.x >> 17], 1);
        int p1 = atomicAdd(&dcur[w4.y >> 17], 1);
        int p2 = atomicAdd(&dcur[w4.z >> 17], 1);
        int p3 = atomicAdd(&dcur[w4.w >> 17], 1);
        slots[p0] = (int)(w4.x & 0x1ffffu);
        slots[p1] = (int)(w4.y & 0x1ffffu);
        slots[p2] = (int)(w4.z & 0x1ffffu);
        slots[p3] = (int)(w4.w & 0x1ffffu);
    }
    for (; i < cnt; ++i) {
        unsigned int w = binned[start + i];
        int pos = atomicAdd(&dcur[w >> 17], 1);
        slots[pos] = (int)(w & 0x1ffffu);
    }
}

// ---------------------------------------------------------------------------
// Gather: 64 lanes per node, 2 cols per lane (bf16x2 h loads). Edge loop
// unrolled x8 with double int4 slot prefetch, fused ELU, no atomics.
// ---------------------------------------------------------------------------
__global__ __launch_bounds__(256) void gather_kernel(
    const int* __restrict__ slots, const int* __restrict__ offsets,
    const int* __restrict__ deg,
    const unsigned int* __restrict__ hv,    // [N*64] packed bf16 pairs
    const float2* __restrict__ usrc, const float2* __restrict__ vdst,
    float* __restrict__ out, int n_nodes)
{
    const int t = threadIdx.x;
    const int node = blockIdx.x * 4 + (t >> 6);
    if (node >= n_nodes) return;
    const int l = t & 63;          // cols {2l, 2l+1}
    const int head = l >> 4;
    const float2 u = usrc[node * NH + head];
    const int beg = offsets[node]; // multiple of 4
    const int d = deg[node];

    float ax0 = 0.f, ay0 = 0.f, ax1 = 0.f, ay1 = 0.f;
    float ax2 = 0.f, ay2 = 0.f, ax3 = 0.f, ay3 = 0.f;
    int k = 0;
    int4 d0, d1;
    if (d >= 8) {
        d0 = *(const int4*)(slots + beg);
        d1 = *(const int4*)(slots + beg + 4);
    }
    for (; k + 8 <= d; k += 8) {
        const int4 c0 = d0, c1 = d1;
        if (k + 16 <= d) {
            d0 = *(const int4*)(slots + beg + k + 8);
            d1 = *(const int4*)(slots + beg + k + 12);
        }
        float2 v0 = vdst[c0.x * NH + head];
        float2 v1 = vdst[c0.y * NH + head];
        float2 v2 = vdst[c0.z * NH + head];
        float2 v3 = vdst[c0.w * NH + head];
        float2 v4 = vdst[c1.x * NH + head];
        float2 v5 = vdst[c1.y * NH + head];
        float2 v6 = vdst[c1.z * NH + head];
        float2 v7 = vdst[c1.w * NH + head];
        unsigned int w0 = hv[(size_t)c0.x * 64 + l];
        unsigned int w1 = hv[(size_t)c0.y * 64 + l];
        unsigned int w2 = hv[(size_t)c0.z * 64 + l];
        unsigned int w3 = hv[(size_t)c0.w * 64 + l];
        unsigned int w4 = hv[(size_t)c1.x * 64 + l];
        unsigned int w5 = hv[(size_t)c1.y * 64 + l];
        unsigned int w6 = hv[(size_t)c1.z * 64 + l];
        unsigned int w7 = hv[(size_t)c1.w * 64 + l];
        float e0 = fminf(u.x * v0.x, u.y * v0.y);
        float e1 = fminf(u.x * v1.x, u.y * v1.y);
        float e2 = fminf(u.x * v2.x, u.y * v2.y);
        float e3 = fminf(u.x * v3.x, u.y * v3.y);
        float e4 = fminf(u.x * v4.x, u.y * v4.y);
        float e5 = fminf(u.x * v5.x, u.y * v5.y);
        float e6 = fminf(u.x * v6.x, u.y * v6.y);
        float e7 = fminf(u.x * v7.x, u.y * v7.y);
        ax0 = fmaf(e0, __uint_as_float(w0 << 16), ax0);
        ay0 = fmaf(e0, __uint_as_float(w0 & 0xffff0000u), ay0);
        ax1 = fmaf(e1, __uint_as_float(w1 << 16), ax1);
        ay1 = fmaf(e1, __uint_as_float(w1 & 0xffff0000u), ay1);
        ax2 = fmaf(e2, __uint_as_float(w2 << 16), ax2);
        ay2 = fmaf(e2, __uint_as_float(w2 & 0xffff0000u), ay2);
        ax3 = fmaf(e3, __uint_as_float(w3 << 16), ax3);
        ay3 = fmaf(e3, __uint_as_float(w3 & 0xffff0000u), ay3);
        ax0 = fmaf(e4, __uint_as_float(w4 << 16), ax0);
        ay0 = fmaf(e4, __uint_as_float(w4 & 0xffff0000u), ay0);
        ax1 = fmaf(e5, __uint_as_float(w5 << 16), ax1);
        ay1 = fmaf(e5, __uint_as_float(w5 & 0xffff0000u), ay1);
        ax2 = fmaf(e6, __uint_as_float(w6 << 16), ax2);
        ay2 = fmaf(e6, __uint_as_float(w6 & 0xffff0000u), ay2);
        ax3 = fmaf(e7, __uint_as_float(w7 << 16), ax3);
        ay3 = fmaf(e7, __uint_as_float(w7 & 0xffff0000u), ay3);
    }
    for (; k < d; ++k) {
        int dst = slots[beg + k];
        float2 v = vdst[dst * NH + head];
        unsigned int w = hv[(size_t)dst * 64 + l];
        float e = fminf(u.x * v.x, u.y * v.y);
        ax0 = fmaf(e, __uint_as_float(w << 16), ax0);
        ay0 = fmaf(e, __uint_as_float(w & 0xffff0000u), ay0);
    }
    float rx = (ax0 + ax1) + (ax2 + ax3);
    float ry = (ay0 + ay1) + (ay2 + ay3);
    rx = rx > 0.f ? rx : __expf(rx) - 1.f;
    ry = ry > 0.f ? ry : __expf(ry) - 1.f;
    ((float2*)out)[(size_t)node * 64 + l] = make_float2(rx, ry);
}

extern "C" void kernel_launch(void* const* d_in, const int* in_sizes, int n_in,
                              void* d_out, int out_size, void* d_ws, size_t ws_size,
                              hipStream_t stream)
{
    const float* x  = (const float*)d_in[0];
    const float* W  = (const float*)d_in[1];
    const float* a  = (const float*)d_in[2];
    const int* esrc = (const int*)d_in[3];
    const int* edst = (const int*)d_in[4];
    const int n_nodes = in_sizes[0] / DIN;
    const int n_edges = in_sizes[3];
    float* out = (float*)d_out;

    const int nb = (n_nodes + BNODES - 1) >> BSH;

    // workspace layout
    unsigned int* hq = (unsigned int*)d_ws;                 // [N*64] bf16 pairs
    float2* usrc = (float2*)(hq + (size_t)n_nodes * 64);    // [N*4]
    float2* vdst = usrc + (size_t)n_nodes * NH;             // [N*4]
    int* offs   = (int*)(vdst + (size_t)n_nodes * NH);      // [N]
    int* deg    = offs + n_nodes;                           // [N]
    int* counts = deg + n_nodes;                            // [MAXB*CPAD]
    int* gcur   = counts + MAXB * CPAD;                     // [MAXB*CPAD]
    int* bbase  = gcur + MAXB * CPAD;                       // [MAXB]
    int* sbase  = bbase + MAXB;                             // [MAXB]
    unsigned int* binned = (unsigned int*)(sbase + MAXB);   // [E + 4*nb + 64]
    int* slots  = (int*)(binned + n_edges + 4 * MAXB + 64); // [E + 512*nb + 64]

    hipMemsetAsync(counts, 0, MAXB * CPAD * sizeof(int), stream);

    feat_kernel<<<(n_nodes + NPB - 1) / NPB, 256, 0, stream>>>(
        x, W, a, hq, usrc, vdst, n_nodes);

    const int binblocks = (n_edges + EPB - 1) / EPB;
    bincount_kernel<<<binblocks, 256, 0, stream>>>(esrc, counts, n_edges, nb);
    bscan_kernel<<<1, 1024, 0, stream>>>(counts, bbase, gcur, sbase, nb);
    binscatter_kernel<<<binblocks, 256, 0, stream>>>(
        esrc, edst, gcur, binned, n_edges, nb);
    binfine_kernel<<<nb, 256, 0, stream>>>(
        binned, counts, bbase, sbase, offs, deg, slots, n_nodes);

    gather_kernel<<<(n_nodes + 3) / 4, 256, 0, stream>>>(
        slots, offs, deg, hq, usrc, vdst, out, n_nodes);
}